// Round 3
// baseline (186.349 us; speedup 1.0000x reference)
//
#include <hip/hip_runtime.h>

// CubePadding: x [B,6,C,H,W] fp32 -> out [B,6,C,H+2P,W+2P] fp32. Pure gather/copy.
// R2: blockIdx.y = plane ((b*6+f)*C+c) -> face/plane decode on scalar unit (SGPRs).
//     Per-thread decode is a single magic-div by 33. Fast path = one (possibly
//     unaligned) 16B load + one aligned 16B store.
// Face order: 0=back(fb) 1=down(fd) 2=front(ff) 3=left(fl) 4=right(fr) 5=top(ft)

constexpr int P = 2, B = 4, C = 64, H = 128, W = 128;
constexpr int Ho = H + 2 * P, Wo = W + 2 * P;
constexpr int NV = Wo / 4;                 // 33 float4 groups per row
constexpr int PLANES = B * 6 * C;          // 1536
constexpr int PER_PLANE = Ho * NV;         // 4356 thread-slots per plane

typedef float vfloat4 __attribute__((ext_vector_type(4)));
typedef vfloat4 float4u __attribute__((aligned(4)));   // unaligned 16B load -> dwordx4

// ---- halo source maps (verified R0/R1) ----
__device__ __forceinline__ void top_map(int f, int t, int w, int& sf, int& r, int& col) {
    switch (f) {
        case 0:  sf = 5; r = P - 1 - t; col = w;         break;
        case 1:  sf = 2; r = H - P + t; col = w;         break;
        case 2:  sf = 5; r = H - P + t; col = w;         break;
        case 3:  sf = 5; r = w;         col = t;         break;
        case 4:  sf = 5; r = w;         col = W - 1 - t; break;
        default: sf = 0; r = P - 1 - t; col = w;         break;
    }
}
__device__ __forceinline__ void bot_map(int f, int t, int w, int& sf, int& r, int& col) {
    switch (f) {
        case 0:  sf = 1; r = H - 1 - t; col = w;         break;
        case 1:  sf = 0; r = H - 1 - t; col = w;         break;
        case 2:  sf = 1; r = t;         col = w;         break;
        case 3:  sf = 1; r = w;         col = P - 1 - t; break;
        case 4:  sf = 1; r = w;         col = W - P + t; break;
        default: sf = 2; r = t;         col = w;         break;
    }
}
__device__ __forceinline__ void lft_map(int f, int h, int l, int& sf, int& r, int& col) {
    switch (f) {
        case 0:  sf = 4; r = h;         col = W - P + l; break;
        case 1:  sf = 3; r = H - 1 - l; col = h;         break;
        case 2:  sf = 3; r = h;         col = W - P + l; break;
        case 3:  sf = 0; r = h;         col = W - P + l; break;
        case 4:  sf = 2; r = h;         col = W - P + l; break;
        default: sf = 3; r = l;         col = h;         break;
    }
}
__device__ __forceinline__ void rgt_map(int f, int h, int rr, int& sf, int& r, int& col) {
    switch (f) {
        case 0:  sf = 3; r = h;          col = rr;        break;
        case 1:  sf = 4; r = H - P + rr; col = h;         break;
        case 2:  sf = 4; r = h;          col = rr;        break;
        case 3:  sf = 2; r = h;          col = rr;        break;
        case 4:  sf = 0; r = h;          col = rr;        break;
        default: sf = 4; r = P - 1 - rr; col = h;         break;
    }
}
__device__ __forceinline__ void gen_map(int f, int i, int j, int& sf, int& r, int& col) {
    bool in_h = (i >= P) && (i < H + P);
    bool in_w = (j >= P) && (j < W + P);
    if (in_h && in_w) {
        sf = f; r = i - P; col = j - P;
    } else if (!in_h) {
        int w = in_w ? (j - P) : (j < P ? 0 : W - 1);   // corners replicate strip edge
        if (i < P) top_map(f, i, w, sf, r, col);
        else       bot_map(f, i - H - P, w, sf, r, col);
    } else {
        if (j < P) lft_map(f, i - P, j,         sf, r, col);
        else       rgt_map(f, i - P, j - W - P, sf, r, col);
    }
}

__global__ __launch_bounds__(256) void cubepad_p_kernel(const float* __restrict__ x,
                                                        float* __restrict__ out) {
    const int plane = blockIdx.y;                 // (b*6+f)*C + c  — SGPR
    const int f  = (plane / C) % 6;               // SGPR
    const int bC = plane - f * C;                 // b*6*C + c — SGPR
    const float* __restrict__ xp = x + (size_t)plane * (H * W);    // fast-path src plane
    float*       __restrict__ op = out + (size_t)plane * (Ho * Wo);

    int tx = blockIdx.x * 256 + threadIdx.x;
    if (tx >= PER_PLANE) return;
    int i = tx / NV;                              // one magic-mul div
    int v = tx - i * NV;

    float4 val;
    bool fast = (i >= P) && (i < H + P) && (v >= 1) && (v < NV - 1);
    if (fast) {
        // src cols 4v-2 .. 4v+1 of row i-P; 8B-aligned start, single dwordx4 if HW allows
        const float* s = xp + (i - P) * W + (4 * v - P);
        float4u t = *(const float4u*)s;
        val = make_float4(t.x, t.y, t.z, t.w);
    } else {
        float* vp = (float*)&val;
        #pragma unroll
        for (int e = 0; e < 4; ++e) {
            int sf, r, col;
            gen_map(f, i, 4 * v + e, sf, r, col);
            vp[e] = x[((size_t)(bC + sf * C)) * (H * W) + (size_t)r * W + col];
        }
    }
    *(float4*)(op + i * Wo + 4 * v) = val;
}

extern "C" void kernel_launch(void* const* d_in, const int* in_sizes, int n_in,
                              void* d_out, int out_size, void* d_ws, size_t ws_size,
                              hipStream_t stream) {
    const float* x = (const float*)d_in[0];
    float* out = (float*)d_out;
    dim3 grid((PER_PLANE + 255) / 256, PLANES);
    cubepad_p_kernel<<<grid, 256, 0, stream>>>(x, out);
}